// Round 13
// baseline (97.351 us; speedup 1.0000x reference)
//
#include <hip/hip_runtime.h>
#include <hip/hip_bf16.h>

// Problem constants
#define B_    8
#define QLEN  2048
#define D_    1024
#define H_    16
#define KV_   256
#define HD_   64

typedef float fvec4 __attribute__((ext_vector_type(4)));

// ws layout (float offsets) — total 278544 floats = 1.114 MB (R5-proven size):
#define WS_KVEC 0        // B x 1024
#define WS_VVEC 8192     // B x 1024
#define WS_C2   16384    // B
#define WS_SW1  16392    // 1
#define WS_L    16400    // 256K floats: L[b][h][q] flat

__device__ inline float wave_sum(float v) {
#pragma unroll
  for (int off = 32; off > 0; off >>= 1) v += __shfl_xor(v, off, 64);
  return v;
}
template <int N>
__device__ inline void multi_sum(float* v) {
#pragma unroll
  for (int off = 32; off > 0; off >>= 1) {
#pragma unroll
    for (int r = 0; r < N; ++r) v[r] += __shfl_xor(v[r], off, 64);
  }
}

// Kernel 1: Kvec/Vvec GEMVs. Weights read ONCE (8 MB) at 2048-wave
// parallelism. Block 512: c2 + sw1.  (R8/R10-validated)
__global__ __launch_bounds__(256) void prep_kernel(
    const float* __restrict__ key, const float* __restrict__ value,
    const float* __restrict__ kw, const float* __restrict__ vw,
    const float* __restrict__ clip, const float* __restrict__ scale_w,
    float* __restrict__ ws) {
  const int lane = threadIdx.x & 63;
  const int waveId = threadIdx.x >> 6;

  if (blockIdx.x == 512) {
    if (waveId != 0) return;
    const fvec4* sw4 = reinterpret_cast<const fvec4*>(scale_w);
    fvec4 a = sw4[lane];                       // scale_w[0..255]
    float s = wave_sum(a.x + a.y + a.z + a.w);
    if (lane == 0) ws[WS_SW1] = s;
    fvec4 w2 = sw4[64 + lane];                 // scale_w[256..511]
    for (int b = 0; b < B_; ++b) {
      const fvec4* c4 = reinterpret_cast<const fvec4*>(clip + b * KV_);
      fvec4 c = c4[lane];
      float p = c.x * w2.x + c.y * w2.y + c.z * w2.z + c.w * w2.w;
      p = wave_sum(p);
      if (lane == 0) ws[WS_C2 + b] = p;
    }
    return;
  }

  const int W = blockIdx.x * 4 + waveId;  // 0..2047
  const int sel = W >> 10;                // 0=K, 1=V
  const int d = W & 1023;                 // output row
  const float* Wt = sel ? vw : kw;
  const float* xsrc = sel ? value : key;
  float* outv = ws + (sel ? WS_VVEC : WS_KVEC);

  const fvec4* w4 = reinterpret_cast<const fvec4*>(Wt + (size_t)d * 1024);
  fvec4 wr[4];
#pragma unroll
  for (int i = 0; i < 4; ++i) wr[i] = w4[i * 64 + lane];

#pragma unroll
  for (int b0 = 0; b0 < B_; b0 += 2) {
    const fvec4* xa = reinterpret_cast<const fvec4*>(xsrc + b0 * 1024);
    const fvec4* xb = reinterpret_cast<const fvec4*>(xsrc + (b0 + 1) * 1024);
    float acc[2] = {0.f, 0.f};
#pragma unroll
    for (int i = 0; i < 4; ++i) {
      fvec4 x0 = xa[i * 64 + lane];
      fvec4 x1 = xb[i * 64 + lane];
      acc[0] += x0.x * wr[i].x + x0.y * wr[i].y + x0.z * wr[i].z + x0.w * wr[i].w;
      acc[1] += x1.x * wr[i].x + x1.y * wr[i].y + x1.z * wr[i].z + x1.w * wr[i].w;
    }
    multi_sum<2>(acc);
    if (lane == 0) {
      outv[b0 * 1024 + d] = acc[0];
      outv[(b0 + 1) * 1024 + d] = acc[1];
    }
  }
}

// Kernel 2: L[row] = sw1 * dot(Q_row, Kvec_head)/8 + c2[b] + scale_b.
// Wave owns 16 rows; float4 Q loads; 16-lane group reductions. (R5/R10-validated)
__global__ __launch_bounds__(256) void qdot_kernel(
    const float* __restrict__ query, const float* __restrict__ scale_b,
    float* __restrict__ ws) {
  const int lane = threadIdx.x & 63;
  const int waveId = threadIdx.x >> 6;
  const int rowBase = blockIdx.x * 64 + waveId * 16;  // flat (b,h,q)
  const int b = rowBase >> 15;
  const int h = (rowBase >> 11) & 15;
  const int q0 = rowBase & 2047;
  const int g = lane >> 4;   // row sub-group 0..3
  const int c = lane & 15;   // float4 column within 64-dim head slice

  const fvec4 kvv = reinterpret_cast<const fvec4*>(ws + WS_KVEC + b * 1024 + h * HD_)[c];
  const float sw1 = ws[WS_SW1];
  const float Lc = ws[WS_C2 + b] + scale_b[0];

  const float* qb = query + ((size_t)(b * QLEN + q0)) * D_ + h * HD_;
  float p[4];
#pragma unroll
  for (int j = 0; j < 4; ++j) {
    const fvec4 q4 = __builtin_nontemporal_load(
        reinterpret_cast<const fvec4*>(qb + (size_t)(j * 4 + g) * D_) + c);
    p[j] = q4.x * kvv.x + q4.y * kvv.y + q4.z * kvv.z + q4.w * kvv.w;
  }
#pragma unroll
  for (int off = 1; off <= 8; off <<= 1) {
#pragma unroll
    for (int j = 0; j < 4; ++j) p[j] += __shfl_xor(p[j], off, 64);
  }
  if (c < 4) {
    const float sp = (c == 0) ? p[0] : (c == 1) ? p[1] : (c == 2) ? p[2] : p[3];
    ws[WS_L + rowBase + c * 4 + g] = sw1 * (sp * 0.125f) + Lc;
  }
}

// Kernel 3: store stream with a GLOBALLY DENSE frontier. Wave w owns rows
// {i*8192 + w}: at instant i, all 8192 waves write one contiguous 8 MB
// window marching linearly through attn (fill-like locality). Group g=i>>2
// corresponds exactly to batch b=g, so clip rows are wave-uniform.
__global__ __launch_bounds__(256) void attn_stream_kernel(
    const float* __restrict__ clip, const float* __restrict__ ws,
    float* __restrict__ attn, float* __restrict__ out) {
  const int lane = threadIdx.x & 63;
  const int w = (blockIdx.x * 256 + threadIdx.x) >> 6;  // wave id 0..8191

  // clip rows for all 8 batches (group g == batch b). Constant indices only.
  fvec4 cl[8];
#pragma unroll
  for (int g = 0; g < 8; ++g)
    cl[g] = reinterpret_cast<const fvec4*>(clip)[g * 64 + lane];

  // 32 L values: lane i (i<32) holds L of row i*8192 + w.
  const float Lv = ws[WS_L + (lane & 31) * 8192 + w];

  // Batched denominators (R10-validated numerics, no max subtraction).
  float t[32];
#pragma unroll
  for (int i = 0; i < 32; ++i) {
    const float Ld = __builtin_amdgcn_readlane(Lv, i);
    const fvec4 c = cl[i >> 2];
    t[i] = __expf(Ld * c.x) + __expf(Ld * c.y) +
           __expf(Ld * c.z) + __expf(Ld * c.w);
  }
  multi_sum<32>(t);

  // Dense-frontier store stream.
  fvec4* a4 = reinterpret_cast<fvec4*>(attn);
#pragma unroll
  for (int i = 0; i < 32; ++i) {
    const int row = i * 8192 + w;
    const float Ld = __builtin_amdgcn_readlane(Lv, i);
    const float rd = __builtin_amdgcn_rcpf(t[i]);
    const fvec4 c = cl[i >> 2];
    fvec4 e;
    e.x = __expf(Ld * c.x) * rd;
    e.y = __expf(Ld * c.y) * rd;
    e.z = __expf(Ld * c.z) * rd;
    e.w = __expf(Ld * c.w) * rd;
    __builtin_nontemporal_store(e, &a4[(size_t)row * 64 + lane]);
  }

  // Out-broadcast, same dense striding: chunk i*8192 + w (1 KB each).
  const fvec4* v4 = reinterpret_cast<const fvec4*>(ws + WS_VVEC);
  fvec4* o4 = reinterpret_cast<fvec4*>(out);
#pragma unroll
  for (int i = 0; i < 8; ++i) {
    const int j = (i * 8192 + w) * 64 + lane;   // fvec4 index
    const int ob = j >> 19;                     // 524288 float4 per batch
    const int d4 = j & 255;
    fvec4 v = v4[ob * 256 + d4];
    __builtin_nontemporal_store(v, &o4[j]);
  }
}

extern "C" void kernel_launch(void* const* d_in, const int* in_sizes, int n_in,
                              void* d_out, int out_size, void* d_ws, size_t ws_size,
                              hipStream_t stream) {
  const float* query   = (const float*)d_in[0];
  const float* key     = (const float*)d_in[1];
  const float* value   = (const float*)d_in[2];
  const float* clip    = (const float*)d_in[3];
  const float* kw      = (const float*)d_in[4];
  const float* vw      = (const float*)d_in[5];
  const float* scale_w = (const float*)d_in[6];
  const float* scale_b = (const float*)d_in[7];
  float* out  = (float*)d_out;
  float* attn = out + (size_t)B_ * QLEN * D_;   // outputs concatenated flat
  float* ws   = (float*)d_ws;

  hipLaunchKernelGGL(prep_kernel, dim3(513), dim3(256), 0, stream,
                     key, value, kw, vw, clip, scale_w, ws);
  hipLaunchKernelGGL(qdot_kernel, dim3(4096), dim3(256), 0, stream,
                     query, scale_b, ws);
  hipLaunchKernelGGL(attn_stream_kernel, dim3(2048), dim3(256), 0, stream,
                     clip, ws, attn, out);
}

// Round 14
// 83.939 us; speedup vs baseline: 1.1598x; 1.1598x over previous
//
#include <hip/hip_runtime.h>
#include <hip/hip_bf16.h>

// Problem constants
#define B_    8
#define QLEN  2048
#define D_    1024
#define H_    16
#define KV_   256
#define HD_   64

typedef float fvec4 __attribute__((ext_vector_type(4)));

// ws layout (float offsets) — total 278544 floats = 1.114 MB (R5-proven size):
#define WS_KVEC 0        // B x 1024
#define WS_VVEC 8192     // B x 1024
#define WS_C2   16384    // B
#define WS_SW1  16392    // 1
#define WS_L    16400    // 256K floats: L[b][h][q] flat

__device__ inline float wave_sum(float v) {
#pragma unroll
  for (int off = 32; off > 0; off >>= 1) v += __shfl_xor(v, off, 64);
  return v;
}
template <int N>
__device__ inline void multi_sum(float* v) {
#pragma unroll
  for (int off = 32; off > 0; off >>= 1) {
#pragma unroll
    for (int r = 0; r < N; ++r) v[r] += __shfl_xor(v[r], off, 64);
  }
}

// Kernel 1: Kvec/Vvec GEMVs. Weights read ONCE (8 MB) at 2048-wave
// parallelism. Block 512: c2 + sw1.  (R8/R10-validated)
__global__ __launch_bounds__(256) void prep_kernel(
    const float* __restrict__ key, const float* __restrict__ value,
    const float* __restrict__ kw, const float* __restrict__ vw,
    const float* __restrict__ clip, const float* __restrict__ scale_w,
    float* __restrict__ ws) {
  const int lane = threadIdx.x & 63;
  const int waveId = threadIdx.x >> 6;

  if (blockIdx.x == 512) {
    if (waveId != 0) return;
    const fvec4* sw4 = reinterpret_cast<const fvec4*>(scale_w);
    fvec4 a = sw4[lane];                       // scale_w[0..255]
    float s = wave_sum(a.x + a.y + a.z + a.w);
    if (lane == 0) ws[WS_SW1] = s;
    fvec4 w2 = sw4[64 + lane];                 // scale_w[256..511]
    for (int b = 0; b < B_; ++b) {
      const fvec4* c4 = reinterpret_cast<const fvec4*>(clip + b * KV_);
      fvec4 c = c4[lane];
      float p = c.x * w2.x + c.y * w2.y + c.z * w2.z + c.w * w2.w;
      p = wave_sum(p);
      if (lane == 0) ws[WS_C2 + b] = p;
    }
    return;
  }

  const int W = blockIdx.x * 4 + waveId;  // 0..2047
  const int sel = W >> 10;                // 0=K, 1=V
  const int d = W & 1023;                 // output row
  const float* Wt = sel ? vw : kw;
  const float* xsrc = sel ? value : key;
  float* outv = ws + (sel ? WS_VVEC : WS_KVEC);

  const fvec4* w4 = reinterpret_cast<const fvec4*>(Wt + (size_t)d * 1024);
  fvec4 wr[4];
#pragma unroll
  for (int i = 0; i < 4; ++i) wr[i] = w4[i * 64 + lane];

#pragma unroll
  for (int b0 = 0; b0 < B_; b0 += 2) {
    const fvec4* xa = reinterpret_cast<const fvec4*>(xsrc + b0 * 1024);
    const fvec4* xb = reinterpret_cast<const fvec4*>(xsrc + (b0 + 1) * 1024);
    float acc[2] = {0.f, 0.f};
#pragma unroll
    for (int i = 0; i < 4; ++i) {
      fvec4 x0 = xa[i * 64 + lane];
      fvec4 x1 = xb[i * 64 + lane];
      acc[0] += x0.x * wr[i].x + x0.y * wr[i].y + x0.z * wr[i].z + x0.w * wr[i].w;
      acc[1] += x1.x * wr[i].x + x1.y * wr[i].y + x1.z * wr[i].z + x1.w * wr[i].w;
    }
    multi_sum<2>(acc);
    if (lane == 0) {
      outv[b0 * 1024 + d] = acc[0];
      outv[(b0 + 1) * 1024 + d] = acc[1];
    }
  }
}

// Kernel 2: L[row] = sw1 * dot(Q_row, Kvec_head)/8 + c2[b] + scale_b.
// Wave owns 16 rows; float4 Q loads; 16-lane group reductions. (R5/R10-validated)
__global__ __launch_bounds__(256) void qdot_kernel(
    const float* __restrict__ query, const float* __restrict__ scale_b,
    float* __restrict__ ws) {
  const int lane = threadIdx.x & 63;
  const int waveId = threadIdx.x >> 6;
  const int rowBase = blockIdx.x * 64 + waveId * 16;  // flat (b,h,q)
  const int b = rowBase >> 15;
  const int h = (rowBase >> 11) & 15;
  const int q0 = rowBase & 2047;
  const int g = lane >> 4;   // row sub-group 0..3
  const int c = lane & 15;   // float4 column within 64-dim head slice

  const fvec4 kvv = reinterpret_cast<const fvec4*>(ws + WS_KVEC + b * 1024 + h * HD_)[c];
  const float sw1 = ws[WS_SW1];
  const float Lc = ws[WS_C2 + b] + scale_b[0];

  const float* qb = query + ((size_t)(b * QLEN + q0)) * D_ + h * HD_;
  float p[4];
#pragma unroll
  for (int j = 0; j < 4; ++j) {
    const fvec4 q4 = __builtin_nontemporal_load(
        reinterpret_cast<const fvec4*>(qb + (size_t)(j * 4 + g) * D_) + c);
    p[j] = q4.x * kvv.x + q4.y * kvv.y + q4.z * kvv.z + q4.w * kvv.w;
  }
#pragma unroll
  for (int off = 1; off <= 8; off <<= 1) {
#pragma unroll
    for (int j = 0; j < 4; ++j) p[j] += __shfl_xor(p[j], off, 64);
  }
  if (c < 4) {
    const float sp = (c == 0) ? p[0] : (c == 1) ? p[1] : (c == 2) ? p[2] : p[3];
    ws[WS_L + rowBase + c * 4 + g] = sw1 * (sp * 0.125f) + Lc;
  }
}

// Kernel 3: store stream (R10 structure, refined): out-broadcast FIRST
// (fills the store pipe during the exp prologue), 16 rows per wave
// (half prologue, half VGPR, 2x waves for occupancy/tail).
__global__ __launch_bounds__(256) void attn_stream_kernel(
    const float* __restrict__ clip, const float* __restrict__ ws,
    float* __restrict__ attn, float* __restrict__ out) {
  const int lane = threadIdx.x & 63;
  const int gwave = (blockIdx.x * 256 + threadIdx.x) >> 6;  // 0..16383
  const int row0 = gwave * 16;
  const int b = row0 >> 15;   // 32768 rows per batch

  // Out-broadcast first: 65536 chunks of 1KB; this wave does 4 contiguous.
  {
    const fvec4* v4 = reinterpret_cast<const fvec4*>(ws + WS_VVEC);
    fvec4* o4 = reinterpret_cast<fvec4*>(out);
#pragma unroll
    for (int i = 0; i < 4; ++i) {
      const int j = (gwave * 4 + i) * 64 + lane;  // float4 index
      const int ob = j >> 19;                     // 524288 float4 per batch
      const int d4 = j & 255;
      fvec4 v = v4[ob * 256 + d4];
      __builtin_nontemporal_store(v, &o4[j]);
    }
  }

  const fvec4 cl = reinterpret_cast<const fvec4*>(clip + b * KV_)[lane];
  // One coalesced 64B read covers this wave's 16 L values.
  const float Lv = ws[WS_L + row0 + (lane & 15)];

  // Batched denominators (R10-validated numerics, no max subtraction).
  float t[16];
#pragma unroll
  for (int i = 0; i < 16; ++i) {
    const float Ld = __builtin_amdgcn_readlane(Lv, i);
    t[i] = __expf(Ld * cl.x) + __expf(Ld * cl.y) +
           __expf(Ld * cl.z) + __expf(Ld * cl.w);
  }
  multi_sum<16>(t);

  // Pure store stream: zero cross-lane ops between stores.
  fvec4* a4 = reinterpret_cast<fvec4*>(attn) + (size_t)row0 * 64 + lane;
#pragma unroll
  for (int i = 0; i < 16; ++i) {
    const float Ld = __builtin_amdgcn_readlane(Lv, i);
    const float rd = __builtin_amdgcn_rcpf(t[i]);
    fvec4 e;
    e.x = __expf(Ld * cl.x) * rd;
    e.y = __expf(Ld * cl.y) * rd;
    e.z = __expf(Ld * cl.z) * rd;
    e.w = __expf(Ld * cl.w) * rd;
    __builtin_nontemporal_store(e, &a4[(size_t)i * 64]);
  }
}

extern "C" void kernel_launch(void* const* d_in, const int* in_sizes, int n_in,
                              void* d_out, int out_size, void* d_ws, size_t ws_size,
                              hipStream_t stream) {
  const float* query   = (const float*)d_in[0];
  const float* key     = (const float*)d_in[1];
  const float* value   = (const float*)d_in[2];
  const float* clip    = (const float*)d_in[3];
  const float* kw      = (const float*)d_in[4];
  const float* vw      = (const float*)d_in[5];
  const float* scale_w = (const float*)d_in[6];
  const float* scale_b = (const float*)d_in[7];
  float* out  = (float*)d_out;
  float* attn = out + (size_t)B_ * QLEN * D_;   // outputs concatenated flat
  float* ws   = (float*)d_ws;

  hipLaunchKernelGGL(prep_kernel, dim3(513), dim3(256), 0, stream,
                     key, value, kw, vw, clip, scale_w, ws);
  hipLaunchKernelGGL(qdot_kernel, dim3(4096), dim3(256), 0, stream,
                     query, scale_b, ws);
  hipLaunchKernelGGL(attn_stream_kernel, dim3(4096), dim3(256), 0, stream,
                     clip, ws, attn, out);
}

// Round 15
// 81.577 us; speedup vs baseline: 1.1934x; 1.0290x over previous
//
#include <hip/hip_runtime.h>
#include <hip/hip_bf16.h>

// Problem constants
#define B_    8
#define QLEN  2048
#define D_    1024
#define H_    16
#define KV_   256
#define HD_   64

typedef float fvec4 __attribute__((ext_vector_type(4)));

// ws layout (float offsets) — total 278544 floats = 1.114 MB (R5-proven size):
#define WS_KVEC 0        // B x 1024
#define WS_VVEC 8192     // B x 1024
#define WS_C2   16384    // B
#define WS_SW1  16392    // 1
#define WS_L    16400    // 256K floats: L[b,h,q]

__device__ inline float wave_sum(float v) {
#pragma unroll
  for (int off = 32; off > 0; off >>= 1) v += __shfl_xor(v, off, 64);
  return v;
}
template <int N>
__device__ inline void multi_sum(float* v) {
#pragma unroll
  for (int off = 32; off > 0; off >>= 1) {
#pragma unroll
    for (int r = 0; r < N; ++r) v[r] += __shfl_xor(v[r], off, 64);
  }
}

// Kernel 1: Kvec/Vvec GEMVs. Weights read ONCE (8 MB) at 2048-wave
// parallelism: one wave per (sel, d-row), looping batches (b-unroll x2).
// Block 512: c2 + sw1.  (R8-validated)
__global__ __launch_bounds__(256) void prep_kernel(
    const float* __restrict__ key, const float* __restrict__ value,
    const float* __restrict__ kw, const float* __restrict__ vw,
    const float* __restrict__ clip, const float* __restrict__ scale_w,
    float* __restrict__ ws) {
  const int lane = threadIdx.x & 63;
  const int waveId = threadIdx.x >> 6;

  if (blockIdx.x == 512) {
    if (waveId != 0) return;
    const fvec4* sw4 = reinterpret_cast<const fvec4*>(scale_w);
    fvec4 a = sw4[lane];                       // scale_w[0..255]
    float s = wave_sum(a.x + a.y + a.z + a.w);
    if (lane == 0) ws[WS_SW1] = s;
    fvec4 w2 = sw4[64 + lane];                 // scale_w[256..511]
    for (int b = 0; b < B_; ++b) {
      const fvec4* c4 = reinterpret_cast<const fvec4*>(clip + b * KV_);
      fvec4 c = c4[lane];
      float p = c.x * w2.x + c.y * w2.y + c.z * w2.z + c.w * w2.w;
      p = wave_sum(p);
      if (lane == 0) ws[WS_C2 + b] = p;
    }
    return;
  }

  const int W = blockIdx.x * 4 + waveId;  // 0..2047
  const int sel = W >> 10;                // 0=K, 1=V
  const int d = W & 1023;                 // output row
  const float* Wt = sel ? vw : kw;
  const float* xsrc = sel ? value : key;
  float* outv = ws + (sel ? WS_VVEC : WS_KVEC);

  const fvec4* w4 = reinterpret_cast<const fvec4*>(Wt + (size_t)d * 1024);
  fvec4 wr[4];
#pragma unroll
  for (int i = 0; i < 4; ++i) wr[i] = w4[i * 64 + lane];

#pragma unroll
  for (int b0 = 0; b0 < B_; b0 += 2) {
    const fvec4* xa = reinterpret_cast<const fvec4*>(xsrc + b0 * 1024);
    const fvec4* xb = reinterpret_cast<const fvec4*>(xsrc + (b0 + 1) * 1024);
    float acc[2] = {0.f, 0.f};
#pragma unroll
    for (int i = 0; i < 4; ++i) {
      fvec4 x0 = xa[i * 64 + lane];
      fvec4 x1 = xb[i * 64 + lane];
      acc[0] += x0.x * wr[i].x + x0.y * wr[i].y + x0.z * wr[i].z + x0.w * wr[i].w;
      acc[1] += x1.x * wr[i].x + x1.y * wr[i].y + x1.z * wr[i].z + x1.w * wr[i].w;
    }
    multi_sum<2>(acc);
    if (lane == 0) {
      outv[b0 * 1024 + d] = acc[0];
      outv[(b0 + 1) * 1024 + d] = acc[1];
    }
  }
}

// Kernel 2: L[row] = sw1 * dot(Q_row, Kvec_head)/8 + c2[b] + scale_b.
// Wave owns 16 rows; float4 Q loads; 16-lane group reductions. (R5-validated)
__global__ __launch_bounds__(256) void qdot_kernel(
    const float* __restrict__ query, const float* __restrict__ scale_b,
    float* __restrict__ ws) {
  const int lane = threadIdx.x & 63;
  const int waveId = threadIdx.x >> 6;
  const int rowBase = blockIdx.x * 64 + waveId * 16;  // flat (b,h,q)
  const int b = rowBase >> 15;
  const int h = (rowBase >> 11) & 15;
  const int q0 = rowBase & 2047;
  const int g = lane >> 4;   // row sub-group 0..3
  const int c = lane & 15;   // float4 column within 64-dim head slice

  const fvec4 kvv = reinterpret_cast<const fvec4*>(ws + WS_KVEC + b * 1024 + h * HD_)[c];
  const float sw1 = ws[WS_SW1];
  const float Lc = ws[WS_C2 + b] + scale_b[0];

  const float* qb = query + ((size_t)(b * QLEN + q0)) * D_ + h * HD_;
  float p[4];
#pragma unroll
  for (int j = 0; j < 4; ++j) {
    const fvec4 q4 = __builtin_nontemporal_load(
        reinterpret_cast<const fvec4*>(qb + (size_t)(j * 4 + g) * D_) + c);
    p[j] = q4.x * kvv.x + q4.y * kvv.y + q4.z * kvv.z + q4.w * kvv.w;
  }
#pragma unroll
  for (int off = 1; off <= 8; off <<= 1) {
#pragma unroll
    for (int j = 0; j < 4; ++j) p[j] += __shfl_xor(p[j], off, 64);
  }
  if (c < 4) {
    const float sp = (c == 0) ? p[0] : (c == 1) ? p[1] : (c == 2) ? p[2] : p[3];
    ws[WS_L + rowBase + c * 4 + g] = sw1 * (sp * 0.125f) + Lc;
  }
}

// Kernel 3: store stream with BATCHED denominators. Wave owns 32 rows:
// one upfront block (128 exps + multi_sum<32>, 6 dependent levels) computes
// all denominators; the store loop is then pure VALU + nt stores.
__global__ __launch_bounds__(256) void attn_stream_kernel(
    const float* __restrict__ clip, const float* __restrict__ ws,
    float* __restrict__ attn, float* __restrict__ out) {
  const int lane = threadIdx.x & 63;
  const int gwave = (blockIdx.x * 256 + threadIdx.x) >> 6;  // 0..8191
  const int row0 = gwave * 32;
  const int b = row0 >> 15;   // 32768 rows per batch

  const fvec4 cl = reinterpret_cast<const fvec4*>(clip + b * KV_)[lane];
  // One coalesced 128B read covers this wave's 32 L values.
  const float Lv = ws[WS_L + row0 + (lane & 31)];

  // Batched denominators: no max subtraction (|L| < ~60 << 88, no overflow;
  // positive-term sums are well-conditioned).  R8-validated numerics.
  float t[32];
#pragma unroll
  for (int i = 0; i < 32; ++i) {
    const float Ld = __builtin_amdgcn_readlane(Lv, i);
    t[i] = __expf(Ld * cl.x) + __expf(Ld * cl.y) +
           __expf(Ld * cl.z) + __expf(Ld * cl.w);
  }
  multi_sum<32>(t);

  // Pure store stream: zero cross-lane ops between stores.
  fvec4* a4 = reinterpret_cast<fvec4*>(attn) + (size_t)row0 * 64 + lane;
#pragma unroll
  for (int i = 0; i < 32; ++i) {
    const float Ld = __builtin_amdgcn_readlane(Lv, i);
    const float rd = __builtin_amdgcn_rcpf(t[i]);
    fvec4 e;
    e.x = __expf(Ld * cl.x) * rd;
    e.y = __expf(Ld * cl.y) * rd;
    e.z = __expf(Ld * cl.z) * rd;
    e.w = __expf(Ld * cl.w) * rd;
    __builtin_nontemporal_store(e, &a4[(size_t)i * 64]);
  }

  // out broadcast: 65536 chunks of 1KB; this wave does 8.
  const fvec4* v4 = reinterpret_cast<const fvec4*>(ws + WS_VVEC);
  fvec4* o4 = reinterpret_cast<fvec4*>(out);
#pragma unroll
  for (int i = 0; i < 8; ++i) {
    const int j = (gwave * 8 + i) * 64 + lane;  // float4 index
    const int ob = j >> 19;                     // 524288 float4 per batch
    const int d4 = j & 255;
    fvec4 v = v4[ob * 256 + d4];
    __builtin_nontemporal_store(v, &o4[j]);
  }
}

extern "C" void kernel_launch(void* const* d_in, const int* in_sizes, int n_in,
                              void* d_out, int out_size, void* d_ws, size_t ws_size,
                              hipStream_t stream) {
  const float* query   = (const float*)d_in[0];
  const float* key     = (const float*)d_in[1];
  const float* value   = (const float*)d_in[2];
  const float* clip    = (const float*)d_in[3];
  const float* kw      = (const float*)d_in[4];
  const float* vw      = (const float*)d_in[5];
  const float* scale_w = (const float*)d_in[6];
  const float* scale_b = (const float*)d_in[7];
  float* out  = (float*)d_out;
  float* attn = out + (size_t)B_ * QLEN * D_;   // outputs concatenated flat
  float* ws   = (float*)d_ws;

  hipLaunchKernelGGL(prep_kernel, dim3(513), dim3(256), 0, stream,
                     key, value, kw, vw, clip, scale_w, ws);
  hipLaunchKernelGGL(qdot_kernel, dim3(4096), dim3(256), 0, stream,
                     query, scale_b, ws);
  hipLaunchKernelGGL(attn_stream_kernel, dim3(2048), dim3(256), 0, stream,
                     clip, ws, attn, out);
}